// Round 5
// baseline (140.368 us; speedup 1.0000x reference)
//
#include <hip/hip_runtime.h>
#include <hip/hip_bf16.h>

// ===========================================================================
// R5 INSTRUMENTATION ROUND — identical kernels to R4 (95.7/96.4us structure).
// ONLY change: pass2 is launched TWICE (it is idempotent: reads x + stats_ws,
// writes deterministic rep-out). dur_us_R5 - dur_us_R4 = per-dispatch time of
// pass2 in harness context, which top-5 profiling hides (<75us fills).
// ===========================================================================

#define LEN 4096
#define BATCH 32
#define CH 256
#define REPN 198
#define GHOSTN 58
#define NROW (REPN * BATCH)     /* 6336 */
#define NGHOST (GHOSTN * BATCH) /* 1856 */
#define CPT 16                  /* outputs per thread in pass1 */

typedef float f32x4 __attribute__((ext_vector_type(4)));

// ---------------------------------------------------------------------------
// COMPILE-TIME numpy-legacy RNG replication (verified rounds 1-8):
// np.random.seed(123); np.random.choice(256, 58, replace=False)
// ---------------------------------------------------------------------------
struct MTState { unsigned mt[624]; int mti; };
struct Tab { int rep[REPN]; int ghost[GHOSTN]; };

static constexpr unsigned mt_next(MTState& s) {
    if (s.mti >= 624) {
        for (int k = 0; k < 624; ++k) {
            unsigned y = (s.mt[k] & 0x80000000u) | (s.mt[(k + 1) % 624] & 0x7fffffffu);
            s.mt[k] = s.mt[(k + 397) % 624] ^ (y >> 1) ^ ((y & 1u) ? 0x9908b0dfu : 0u);
        }
        s.mti = 0;
    }
    unsigned y = s.mt[s.mti++];
    y ^= y >> 11;
    y ^= (y << 7) & 0x9d2c5680u;
    y ^= (y << 15) & 0xefc60000u;
    y ^= y >> 18;
    return y;
}

static constexpr Tab make_tab() {
    MTState s{};
    s.mt[0] = 123u;
    for (int i = 1; i < 624; ++i)
        s.mt[i] = 1812433253u * (s.mt[i - 1] ^ (s.mt[i - 1] >> 30)) + (unsigned)i;
    s.mti = 624;
    int perm[256] = {};
    for (int i = 0; i < 256; ++i) perm[i] = i;
    for (int i = 255; i > 0; --i) {
        unsigned mask = (unsigned)i;
        mask |= mask >> 1; mask |= mask >> 2; mask |= mask >> 4;
        mask |= mask >> 8; mask |= mask >> 16;
        unsigned j = 0;
        do { j = mt_next(s) & mask; } while (j > (unsigned)i);
        int t = perm[i]; perm[i] = perm[j]; perm[j] = t;
    }
    bool g[256] = {};
    for (int k = 0; k < GHOSTN; ++k) g[perm[k]] = true;
    Tab t{};
    int rc = 0, gc = 0;
    for (int c = 0; c < 256; ++c) {
        if (g[c]) t.ghost[gc++] = c;
        else      t.rep[rc++] = c;
    }
    return t;
}

__constant__ Tab d_tab = make_tab();

// ===========================================================================
// Pass 1 — LDS-staged stats, block per rep row. Ghost copy rides along.
// ===========================================================================
__global__ __launch_bounds__(256) void pass1_kernel(const float* __restrict__ x,
                                                    const float* __restrict__ w1,
                                                    const float* __restrict__ w2,
                                                    float* __restrict__ stats_ws,
                                                    float* __restrict__ out) {
    const int blk = blockIdx.x;
    if (blk >= NROW) {
        // ghost pass-through: NT load (never re-read), plain store
        const int g = (blk - NROW) % GHOSTN;
        const int b = (blk - NROW) / GHOSTN;
        const int ch = d_tab.ghost[g];
        const f32x4* src = (const f32x4*)(x + ((size_t)b * CH + ch) * LEN);
        f32x4* dst = (f32x4*)(out + ((size_t)b * CH + REPN + g) * LEN);
#pragma unroll
        for (int k = 0; k < 4; ++k) {
            f32x4 t = __builtin_nontemporal_load(&src[threadIdx.x + 256 * k]);
            dst[threadIdx.x + 256 * k] = t;
        }
        return;
    }
    __shared__ float s[LEN + 16];
    __shared__ float red[6][4];
    const int r = blk % REPN;
    const int b = blk / REPN;
    const int ch = d_tab.rep[r];
    const float* row = x + ((size_t)b * CH + ch) * LEN;

    // Coalesced stage: s[8 + l] = row[l]; zero 8-float halos.
    {
        const f32x4* row4 = (const f32x4*)row;
        f32x4* s4 = (f32x4*)(s + 8);
#pragma unroll
        for (int k = 0; k < 4; ++k) s4[threadIdx.x + 256 * k] = row4[threadIdx.x + 256 * k];
        if (threadIdx.x < 8) { s[threadIdx.x] = 0.f; s[LEN + 8 + threadIdx.x] = 0.f; }
    }

    float w[5][3];
    const float* p1 = w1 + r * 15;
    const float* p2 = w2 + r * 15;
#pragma unroll
    for (int i = 0; i < 5; ++i)
#pragma unroll
        for (int t = 0; t < 3; ++t) w[i][t] = p1[i * 3 + t] + p2[i * 3 + t];
    __syncthreads();

    const int l0 = threadIdx.x * CPT;
    // Thread window: v[k] = row[l0 - 8 + k], 16B-aligned ds_read_b128 x8.
    float v[32];
    {
        const f32x4* sw = (const f32x4*)(s + l0);
#pragma unroll
        for (int k = 0; k < 8; ++k) {
            f32x4 t = sw[k];
            v[4 * k] = t.x; v[4 * k + 1] = t.y; v[4 * k + 2] = t.z; v[4 * k + 3] = t.w;
        }
    }

    // FIR semantics (verified rounds 1-8):
    //   x1 group i: taps v[j+1+3i..j+3+3i], gated on 0 <= l-6+3i < LEN
    //   x2 group i: taps v[j+13-3i..j+15-3i], gated on 0 <= l+6-3i < LEN
    //   x3 = ungated group-2 partial of x1
    float s1 = 0, s1q = 0, s2 = 0, s2q = 0, s3 = 0, s3q = 0;
    const bool edge = (threadIdx.x == 0) | (threadIdx.x == 255);
#define STAT_BODY(GATED)                                                          \
    _Pragma("unroll")                                                             \
    for (int j = 0; j < CPT; ++j) {                                               \
        const int l = l0 + j;                                                     \
        float x1 = 0.f, x2 = 0.f, x3 = 0.f;                                       \
        _Pragma("unroll")                                                         \
        for (int i = 0; i < 5; ++i) {                                             \
            float a1 = fmaf(w[i][0], v[j + 1 + 3 * i],                            \
                       fmaf(w[i][1], v[j + 2 + 3 * i],                            \
                            w[i][2] * v[j + 3 + 3 * i]));                         \
            float a2 = fmaf(w[i][0], v[j + 13 - 3 * i],                           \
                       fmaf(w[i][1], v[j + 14 - 3 * i],                           \
                            w[i][2] * v[j + 15 - 3 * i]));                        \
            if (i == 2) x3 = a1; /* ungated */                                    \
            if (GATED) {                                                          \
                a1 = ((unsigned)(l - 6 + 3 * i) < (unsigned)LEN) ? a1 : 0.f;      \
                a2 = ((unsigned)(l + 6 - 3 * i) < (unsigned)LEN) ? a2 : 0.f;      \
            }                                                                     \
            x1 += a1; x2 += a2;                                                   \
        }                                                                         \
        s1 += x1; s1q = fmaf(x1, x1, s1q);                                        \
        s2 += x2; s2q = fmaf(x2, x2, s2q);                                        \
        s3 += x3; s3q = fmaf(x3, x3, s3q);                                        \
    }
    if (!edge) { STAT_BODY(false) } else { STAT_BODY(true) }
#undef STAT_BODY

#pragma unroll
    for (int off = 32; off > 0; off >>= 1) {
        s1 += __shfl_down(s1, off);  s1q += __shfl_down(s1q, off);
        s2 += __shfl_down(s2, off);  s2q += __shfl_down(s2q, off);
        s3 += __shfl_down(s3, off);  s3q += __shfl_down(s3q, off);
    }
    const int lane = threadIdx.x & 63, wv = threadIdx.x >> 6;
    if (lane == 0) {
        red[0][wv] = s1; red[1][wv] = s1q;
        red[2][wv] = s2; red[3][wv] = s2q;
        red[4][wv] = s3; red[5][wv] = s3q;
    }
    __syncthreads();
    if (threadIdx.x < 6) {
        float t = red[threadIdx.x][0] + red[threadIdx.x][1] +
                  red[threadIdx.x][2] + red[threadIdx.x][3];
        stats_ws[(threadIdx.x * REPN + r) * BATCH + b] = t;
    }
}

// ===========================================================================
// Pass 2 — barrier-free wave-per-row, rep rows ONLY. Plain loads + stores.
// ===========================================================================
__device__ __forceinline__ void load_fast(const float* __restrict__ row, int e, float* v) {
    const f32x4* q4 = (const f32x4*)(row + e - 8);
#pragma unroll
    for (int t = 0; t < 5; ++t) {
        f32x4 u = q4[t];
        v[4 * t] = u.x; v[4 * t + 1] = u.y; v[4 * t + 2] = u.z; v[4 * t + 3] = u.w;
    }
}

__device__ __forceinline__ void load_slow(const float* __restrict__ row, int e, float* v) {
#pragma unroll
    for (int d = 0; d < 20; ++d) {
        int fi = e - 8 + d;
        v[d] = ((unsigned)fi < (unsigned)LEN) ? row[fi] : 0.f;
    }
}

__global__ __launch_bounds__(256) void pass2_kernel(const float* __restrict__ x,
                                                    const float* __restrict__ w1,
                                                    const float* __restrict__ w2,
                                                    const float* __restrict__ stats_ws,
                                                    const float* __restrict__ g1, const float* __restrict__ b1,
                                                    const float* __restrict__ g2, const float* __restrict__ b2,
                                                    const float* __restrict__ g3, const float* __restrict__ b3,
                                                    float* __restrict__ out) {
    const int wv = (blockIdx.x << 2) | (threadIdx.x >> 6);
    const int lane = threadIdx.x & 63;
    const int r = wv % REPN;
    const int b = wv / REPN;
    const int ch = d_tab.rep[r];
    const float* row = x + ((size_t)b * CH + ch) * LEN;

    // BN finalize: lanes load the 32 batch partials (dup across halves), butterfly.
    float p[6];
    const int bb = lane & 31;
#pragma unroll
    for (int q = 0; q < 6; ++q) p[q] = stats_ws[(q * REPN + r) * BATCH + bb];
#pragma unroll
    for (int m = 1; m < 32; m <<= 1)
#pragma unroll
        for (int q = 0; q < 6; ++q) p[q] += __shfl_xor(p[q], m);

    const double invN = 1.0 / (double)(BATCH * LEN);
    float sc[3], sh[3];
    {
        const float gr[3] = {g1[r], g2[r], g3[r]};
        const float br[3] = {b1[r], b2[r], b3[r]};
#pragma unroll
        for (int q = 0; q < 3; ++q) {
            double mean = (double)p[2 * q] * invN;
            double var = (double)p[2 * q + 1] * invN - mean * mean;
            double inv = 1.0 / sqrt(var + 1e-5);
            double scale = (double)gr[q] * inv;
            sc[q] = (float)scale;
            sh[q] = (float)((double)br[q] - mean * scale);
        }
    }
    const float base = sh[0] + sh[1] + sh[2];

    float wb[5][3];
    const float* p1 = w1 + r * 15;
    const float* p2 = w2 + r * 15;
#pragma unroll
    for (int i = 0; i < 5; ++i)
#pragma unroll
        for (int t = 0; t < 3; ++t) wb[i][t] = p1[i * 3 + t] + p2[i * 3 + t];

    // Combined 15-tap filter (interior): tap d=3k+t applies to v[j+1+d].
    float c[15];
#pragma unroll
    for (int k = 0; k < 5; ++k)
#pragma unroll
        for (int t = 0; t < 3; ++t)
            c[3 * k + t] = fmaf(sc[0], wb[k][t], sc[1] * wb[4 - k][t]);
#pragma unroll
    for (int t = 0; t < 3; ++t) c[6 + t] = fmaf(sc[2], wb[2][t], c[6 + t]);

    float* orow = out + ((size_t)b * CH + r) * LEN;
    float v[20];

#define INTERIOR_QUAD(E)                                                          \
    {                                                                             \
        float o[4];                                                               \
        _Pragma("unroll")                                                         \
        for (int j = 0; j < 4; ++j) {                                             \
            float acc = base + v[j + 8];                                          \
            _Pragma("unroll")                                                     \
            for (int d = 0; d < 15; ++d) acc = fmaf(c[d], v[j + 1 + d], acc);     \
            o[j] = acc;                                                           \
        }                                                                         \
        f32x4 t = {o[0], o[1], o[2], o[3]};                                       \
        *(f32x4*)(orow + (E)) = t;                                                \
    }

#define EDGE_QUAD(E)                                                              \
    {                                                                             \
        float o[4];                                                               \
        _Pragma("unroll")                                                         \
        for (int j = 0; j < 4; ++j) {                                             \
            const int l = (E) + j;                                                \
            float x1 = 0.f, x2 = 0.f, x3 = 0.f;                                   \
            _Pragma("unroll")                                                     \
            for (int i = 0; i < 5; ++i) {                                         \
                float a1 = fmaf(wb[i][0], v[j + 1 + 3 * i],                       \
                           fmaf(wb[i][1], v[j + 2 + 3 * i],                       \
                                wb[i][2] * v[j + 3 + 3 * i]));                    \
                float a2 = fmaf(wb[i][0], v[j + 13 - 3 * i],                      \
                           fmaf(wb[i][1], v[j + 14 - 3 * i],                      \
                                wb[i][2] * v[j + 15 - 3 * i]));                   \
                if (i == 2) x3 = a1;                                              \
                a1 = ((unsigned)(l - 6 + 3 * i) < (unsigned)LEN) ? a1 : 0.f;      \
                a2 = ((unsigned)(l + 6 - 3 * i) < (unsigned)LEN) ? a2 : 0.f;      \
                x1 += a1; x2 += a2;                                               \
            }                                                                     \
            o[j] = fmaf(sc[0], x1, fmaf(sc[1], x2, fmaf(sc[2], x3, base + v[j + 8]))); \
        }                                                                         \
        f32x4 t = {o[0], o[1], o[2], o[3]};                                       \
        *(f32x4*)(orow + (E)) = t;                                                \
    }

    { // k = 0
        const int e = 4 * lane;
        if (lane < 2) { load_slow(row, e, v); EDGE_QUAD(e); }
        else          { load_fast(row, e, v); INTERIOR_QUAD(e); }
    }
#pragma unroll
    for (int k = 1; k < 15; ++k) {
        const int e = 4 * lane + 256 * k;
        load_fast(row, e, v);
        INTERIOR_QUAD(e);
    }
    { // k = 15
        const int e = 4 * lane + 3840;
        if (lane >= 62) { load_slow(row, e, v); EDGE_QUAD(e); }
        else            { load_fast(row, e, v); INTERIOR_QUAD(e); }
    }
#undef INTERIOR_QUAD
#undef EDGE_QUAD
}

extern "C" void kernel_launch(void* const* d_in, const int* in_sizes, int n_in,
                              void* d_out, int out_size, void* d_ws, size_t ws_size,
                              hipStream_t stream) {
    const float* x  = (const float*)d_in[0];
    const float* w1 = (const float*)d_in[1];
    const float* w2 = (const float*)d_in[2];
    const float* g1 = (const float*)d_in[3];
    const float* b1 = (const float*)d_in[4];
    const float* g2 = (const float*)d_in[5];
    const float* b2 = (const float*)d_in[6];
    const float* g3 = (const float*)d_in[7];
    const float* b3 = (const float*)d_in[8];
    float* out = (float*)d_out;
    float* stats_ws = (float*)d_ws;   // 6*198*32 floats = 152 KB

    // pass1: 6336 rep blocks (LDS stats) + 1856 ghost copy blocks.
    pass1_kernel<<<NROW + NGHOST, 256, 0, stream>>>(x, w1, w2, stats_ws, out);
    // pass2 launched TWICE (idempotent) — dur_us delta vs R4 = one pass2.
    pass2_kernel<<<1584, 256, 0, stream>>>(x, w1, w2, stats_ws,
                                           g1, b1, g2, b2, g3, b3, out);
    pass2_kernel<<<1584, 256, 0, stream>>>(x, w1, w2, stats_ws,
                                           g1, b1, g2, b2, g3, b3, out);
}

// Round 6
// 91.361 us; speedup vs baseline: 1.5364x; 1.5364x over previous
//
#include <hip/hip_runtime.h>
#include <hip/hip_bf16.h>

#define LEN 4096
#define BATCH 32
#define CH 256
#define REPN 198
#define GHOSTN 58
#define NROW (REPN * BATCH)     /* 6336 */
#define NGHOST (GHOSTN * BATCH) /* 1856 */
#define P1REPBLK 1584           /* 6336 rep waves / 4 waves per block */

typedef float f32x4 __attribute__((ext_vector_type(4)));

// ---------------------------------------------------------------------------
// COMPILE-TIME numpy-legacy RNG replication (verified rounds 1-8):
// np.random.seed(123); np.random.choice(256, 58, replace=False)
// ---------------------------------------------------------------------------
struct MTState { unsigned mt[624]; int mti; };
struct Tab { int rep[REPN]; int ghost[GHOSTN]; };

static constexpr unsigned mt_next(MTState& s) {
    if (s.mti >= 624) {
        for (int k = 0; k < 624; ++k) {
            unsigned y = (s.mt[k] & 0x80000000u) | (s.mt[(k + 1) % 624] & 0x7fffffffu);
            s.mt[k] = s.mt[(k + 397) % 624] ^ (y >> 1) ^ ((y & 1u) ? 0x9908b0dfu : 0u);
        }
        s.mti = 0;
    }
    unsigned y = s.mt[s.mti++];
    y ^= y >> 11;
    y ^= (y << 7) & 0x9d2c5680u;
    y ^= (y << 15) & 0xefc60000u;
    y ^= y >> 18;
    return y;
}

static constexpr Tab make_tab() {
    MTState s{};
    s.mt[0] = 123u;
    for (int i = 1; i < 624; ++i)
        s.mt[i] = 1812433253u * (s.mt[i - 1] ^ (s.mt[i - 1] >> 30)) + (unsigned)i;
    s.mti = 624;
    int perm[256] = {};
    for (int i = 0; i < 256; ++i) perm[i] = i;
    for (int i = 255; i > 0; --i) {
        unsigned mask = (unsigned)i;
        mask |= mask >> 1; mask |= mask >> 2; mask |= mask >> 4;
        mask |= mask >> 8; mask |= mask >> 16;
        unsigned j = 0;
        do { j = mt_next(s) & mask; } while (j > (unsigned)i);
        int t = perm[i]; perm[i] = perm[j]; perm[j] = t;
    }
    bool g[256] = {};
    for (int k = 0; k < GHOSTN; ++k) g[perm[k]] = true;
    Tab t{};
    int rc = 0, gc = 0;
    for (int c = 0; c < 256; ++c) {
        if (g[c]) t.ghost[gc++] = c;
        else      t.rep[rc++] = c;
    }
    return t;
}

__constant__ Tab d_tab = make_tab();

// ---------------------------------------------------------------------------
// Overlapping-window loads: v[d] = row[e-8+d], d<20. Consecutive lanes
// overlap 80B windows at 16B stride -> L1 absorbs the 5x amplification,
// HBM side stays fully coalesced.
// ---------------------------------------------------------------------------
__device__ __forceinline__ void load_fast(const float* __restrict__ row, int e, float* v) {
    const f32x4* q4 = (const f32x4*)(row + e - 8);
#pragma unroll
    for (int t = 0; t < 5; ++t) {
        f32x4 u = q4[t];
        v[4 * t] = u.x; v[4 * t + 1] = u.y; v[4 * t + 2] = u.z; v[4 * t + 3] = u.w;
    }
}

__device__ __forceinline__ void load_slow(const float* __restrict__ row, int e, float* v) {
#pragma unroll
    for (int d = 0; d < 20; ++d) {
        int fi = e - 8 + d;
        v[d] = ((unsigned)fi < (unsigned)LEN) ? row[fi] : 0.f;
    }
}

// ===========================================================================
// Pass 1 (R6 rewrite) — barrier-free wave-per-row stats (structure lifted
// from R3 mono phase A, correctness-proven there). No LDS, no barriers:
// R5 instrumentation showed the old LDS-staged pass1 at 52us for 164 MB
// (3.2 TB/s) vs the barrier-free pass2 at ~4.7 TB/s.
//   blocks [0, 1584)      : 4 waves x 1 rep row each (stats only)
//   blocks [1584, 3440)   : ghost copy, one row per block
// FIR semantics (verified rounds 1-8):
//   x1 group i: taps v[j+1+3i..j+3+3i], gated on 0 <= l-6+3i < LEN
//   x2 group i: taps v[j+13-3i..j+15-3i], gated on 0 <= l+6-3i < LEN
//   x3 = ungated group-2 partial of x1
// ===========================================================================
__global__ __launch_bounds__(256) void pass1_kernel(const float* __restrict__ x,
                                                    const float* __restrict__ w1,
                                                    const float* __restrict__ w2,
                                                    float* __restrict__ stats_ws,
                                                    float* __restrict__ out) {
    const int blk = blockIdx.x;
    if (blk >= P1REPBLK) {
        // ghost pass-through: NT load (never re-read), plain store
        const int g = (blk - P1REPBLK) % GHOSTN;
        const int b = (blk - P1REPBLK) / GHOSTN;
        const int ch = d_tab.ghost[g];
        const f32x4* src = (const f32x4*)(x + ((size_t)b * CH + ch) * LEN);
        f32x4* dst = (f32x4*)(out + ((size_t)b * CH + REPN + g) * LEN);
#pragma unroll
        for (int k = 0; k < 4; ++k) {
            f32x4 t = __builtin_nontemporal_load(&src[threadIdx.x + 256 * k]);
            dst[threadIdx.x + 256 * k] = t;
        }
        return;
    }

    const int wv = (blk << 2) | (threadIdx.x >> 6);
    const int lane = threadIdx.x & 63;
    const int r = wv % REPN;
    const int b = wv / REPN;
    const float* row = x + ((size_t)b * CH + d_tab.rep[r]) * LEN;

    float wb[5][3];
    {
        const float* p1 = w1 + r * 15;
        const float* p2 = w2 + r * 15;
#pragma unroll
        for (int i = 0; i < 5; ++i)
#pragma unroll
            for (int t = 0; t < 3; ++t) wb[i][t] = p1[i * 3 + t] + p2[i * 3 + t];
    }

    float s1 = 0, s1q = 0, s2 = 0, s2q = 0, s3 = 0, s3q = 0;
    float v[20];

#define STATQ(E, GATED)                                                           \
    {                                                                             \
        _Pragma("unroll")                                                         \
        for (int j = 0; j < 4; ++j) {                                             \
            const int l = (E) + j;                                                \
            float x1 = 0.f, x2 = 0.f, x3 = 0.f;                                   \
            _Pragma("unroll")                                                     \
            for (int i = 0; i < 5; ++i) {                                         \
                float a1 = fmaf(wb[i][0], v[j + 1 + 3 * i],                       \
                           fmaf(wb[i][1], v[j + 2 + 3 * i],                       \
                                wb[i][2] * v[j + 3 + 3 * i]));                    \
                float a2 = fmaf(wb[i][0], v[j + 13 - 3 * i],                      \
                           fmaf(wb[i][1], v[j + 14 - 3 * i],                      \
                                wb[i][2] * v[j + 15 - 3 * i]));                   \
                if (i == 2) x3 = a1; /* ungated */                                \
                if (GATED) {                                                      \
                    a1 = ((unsigned)(l - 6 + 3 * i) < (unsigned)LEN) ? a1 : 0.f;  \
                    a2 = ((unsigned)(l + 6 - 3 * i) < (unsigned)LEN) ? a2 : 0.f;  \
                }                                                                 \
                x1 += a1; x2 += a2;                                               \
            }                                                                     \
            s1 += x1; s1q = fmaf(x1, x1, s1q);                                    \
            s2 += x2; s2q = fmaf(x2, x2, s2q);                                    \
            s3 += x3; s3q = fmaf(x3, x3, s3q);                                    \
        }                                                                         \
    }

    { // k = 0: lanes 0,1 contain l < 8 (window underflow + left gating)
        const int e = 4 * lane;
        if (lane < 2) { load_slow(row, e, v); STATQ(e, true); }
        else          { load_fast(row, e, v); STATQ(e, false); }
    }
#pragma unroll 2
    for (int k = 1; k < 15; ++k) {
        const int e = 4 * lane + 256 * k;
        load_fast(row, e, v);
        STATQ(e, false);
    }
    { // k = 15: lanes 62,63 contain l >= 4088 (window overflow + right gating)
        const int e = 4 * lane + 3840;
        if (lane >= 62) { load_slow(row, e, v); STATQ(e, true); }
        else            { load_fast(row, e, v); STATQ(e, false); }
    }
#undef STATQ

    // wave reduce (64 lanes) -> lane 0 writes 6 partials for (r, b)
#pragma unroll
    for (int off = 32; off > 0; off >>= 1) {
        s1 += __shfl_down(s1, off);  s1q += __shfl_down(s1q, off);
        s2 += __shfl_down(s2, off);  s2q += __shfl_down(s2q, off);
        s3 += __shfl_down(s3, off);  s3q += __shfl_down(s3q, off);
    }
    if (lane == 0) {
        stats_ws[(0 * REPN + r) * BATCH + b] = s1;
        stats_ws[(1 * REPN + r) * BATCH + b] = s1q;
        stats_ws[(2 * REPN + r) * BATCH + b] = s2;
        stats_ws[(3 * REPN + r) * BATCH + b] = s2q;
        stats_ws[(4 * REPN + r) * BATCH + b] = s3;
        stats_ws[(5 * REPN + r) * BATCH + b] = s3q;
    }
}

// ===========================================================================
// Pass 2 — barrier-free wave-per-row, rep rows ONLY (unchanged from R4).
// ===========================================================================
__global__ __launch_bounds__(256) void pass2_kernel(const float* __restrict__ x,
                                                    const float* __restrict__ w1,
                                                    const float* __restrict__ w2,
                                                    const float* __restrict__ stats_ws,
                                                    const float* __restrict__ g1, const float* __restrict__ b1,
                                                    const float* __restrict__ g2, const float* __restrict__ b2,
                                                    const float* __restrict__ g3, const float* __restrict__ b3,
                                                    float* __restrict__ out) {
    const int wv = (blockIdx.x << 2) | (threadIdx.x >> 6);
    const int lane = threadIdx.x & 63;
    const int r = wv % REPN;
    const int b = wv / REPN;
    const int ch = d_tab.rep[r];
    const float* row = x + ((size_t)b * CH + ch) * LEN;

    // BN finalize: lanes load the 32 batch partials (dup across halves), butterfly.
    float p[6];
    const int bb = lane & 31;
#pragma unroll
    for (int q = 0; q < 6; ++q) p[q] = stats_ws[(q * REPN + r) * BATCH + bb];
#pragma unroll
    for (int m = 1; m < 32; m <<= 1)
#pragma unroll
        for (int q = 0; q < 6; ++q) p[q] += __shfl_xor(p[q], m);

    const double invN = 1.0 / (double)(BATCH * LEN);
    float sc[3], sh[3];
    {
        const float gr[3] = {g1[r], g2[r], g3[r]};
        const float br[3] = {b1[r], b2[r], b3[r]};
#pragma unroll
        for (int q = 0; q < 3; ++q) {
            double mean = (double)p[2 * q] * invN;
            double var = (double)p[2 * q + 1] * invN - mean * mean;
            double inv = 1.0 / sqrt(var + 1e-5);
            double scale = (double)gr[q] * inv;
            sc[q] = (float)scale;
            sh[q] = (float)((double)br[q] - mean * scale);
        }
    }
    const float base = sh[0] + sh[1] + sh[2];

    float wb[5][3];
    const float* p1 = w1 + r * 15;
    const float* p2 = w2 + r * 15;
#pragma unroll
    for (int i = 0; i < 5; ++i)
#pragma unroll
        for (int t = 0; t < 3; ++t) wb[i][t] = p1[i * 3 + t] + p2[i * 3 + t];

    // Combined 15-tap filter (interior): tap d=3k+t applies to v[j+1+d].
    float c[15];
#pragma unroll
    for (int k = 0; k < 5; ++k)
#pragma unroll
        for (int t = 0; t < 3; ++t)
            c[3 * k + t] = fmaf(sc[0], wb[k][t], sc[1] * wb[4 - k][t]);
#pragma unroll
    for (int t = 0; t < 3; ++t) c[6 + t] = fmaf(sc[2], wb[2][t], c[6 + t]);

    float* orow = out + ((size_t)b * CH + r) * LEN;
    float v[20];

#define INTERIOR_QUAD(E)                                                          \
    {                                                                             \
        float o[4];                                                               \
        _Pragma("unroll")                                                         \
        for (int j = 0; j < 4; ++j) {                                             \
            float acc = base + v[j + 8];                                          \
            _Pragma("unroll")                                                     \
            for (int d = 0; d < 15; ++d) acc = fmaf(c[d], v[j + 1 + d], acc);     \
            o[j] = acc;                                                           \
        }                                                                         \
        f32x4 t = {o[0], o[1], o[2], o[3]};                                       \
        *(f32x4*)(orow + (E)) = t;                                                \
    }

#define EDGE_QUAD(E)                                                              \
    {                                                                             \
        float o[4];                                                               \
        _Pragma("unroll")                                                         \
        for (int j = 0; j < 4; ++j) {                                             \
            const int l = (E) + j;                                                \
            float x1 = 0.f, x2 = 0.f, x3 = 0.f;                                   \
            _Pragma("unroll")                                                     \
            for (int i = 0; i < 5; ++i) {                                         \
                float a1 = fmaf(wb[i][0], v[j + 1 + 3 * i],                       \
                           fmaf(wb[i][1], v[j + 2 + 3 * i],                       \
                                wb[i][2] * v[j + 3 + 3 * i]));                    \
                float a2 = fmaf(wb[i][0], v[j + 13 - 3 * i],                      \
                           fmaf(wb[i][1], v[j + 14 - 3 * i],                      \
                                wb[i][2] * v[j + 15 - 3 * i]));                   \
                if (i == 2) x3 = a1;                                              \
                a1 = ((unsigned)(l - 6 + 3 * i) < (unsigned)LEN) ? a1 : 0.f;      \
                a2 = ((unsigned)(l + 6 - 3 * i) < (unsigned)LEN) ? a2 : 0.f;      \
                x1 += a1; x2 += a2;                                               \
            }                                                                     \
            o[j] = fmaf(sc[0], x1, fmaf(sc[1], x2, fmaf(sc[2], x3, base + v[j + 8]))); \
        }                                                                         \
        f32x4 t = {o[0], o[1], o[2], o[3]};                                       \
        *(f32x4*)(orow + (E)) = t;                                                \
    }

    { // k = 0
        const int e = 4 * lane;
        if (lane < 2) { load_slow(row, e, v); EDGE_QUAD(e); }
        else          { load_fast(row, e, v); INTERIOR_QUAD(e); }
    }
#pragma unroll
    for (int k = 1; k < 15; ++k) {
        const int e = 4 * lane + 256 * k;
        load_fast(row, e, v);
        INTERIOR_QUAD(e);
    }
    { // k = 15
        const int e = 4 * lane + 3840;
        if (lane >= 62) { load_slow(row, e, v); EDGE_QUAD(e); }
        else            { load_fast(row, e, v); INTERIOR_QUAD(e); }
    }
#undef INTERIOR_QUAD
#undef EDGE_QUAD
}

extern "C" void kernel_launch(void* const* d_in, const int* in_sizes, int n_in,
                              void* d_out, int out_size, void* d_ws, size_t ws_size,
                              hipStream_t stream) {
    const float* x  = (const float*)d_in[0];
    const float* w1 = (const float*)d_in[1];
    const float* w2 = (const float*)d_in[2];
    const float* g1 = (const float*)d_in[3];
    const float* b1 = (const float*)d_in[4];
    const float* g2 = (const float*)d_in[5];
    const float* b2 = (const float*)d_in[6];
    const float* g3 = (const float*)d_in[7];
    const float* b3 = (const float*)d_in[8];
    float* out = (float*)d_out;
    float* stats_ws = (float*)d_ws;   // 6*198*32 floats = 152 KB

    // pass1: 1584 rep-stats blocks (wave-per-row, barrier-free)
    //        + 1856 ghost copy blocks.
    pass1_kernel<<<P1REPBLK + NGHOST, 256, 0, stream>>>(x, w1, w2, stats_ws, out);
    // pass2: 6336 rep waves = 1584 blocks (barrier-free, plain stores).
    pass2_kernel<<<1584, 256, 0, stream>>>(x, w1, w2, stats_ws,
                                           g1, b1, g2, b2, g3, b3, out);
}